// Round 7
// baseline (254.687 us; speedup 1.0000x reference)
//
#include <hip/hip_runtime.h>
#include <math.h>

#define N_NODES 50000
#define N_EDGES 800000
#define F 128
#define CAP 64            // bucket capacity per dst; in-deg ~ Poisson(16), P(>=64) ~ 1e-19/node
#define NB 256            // histogram blocks
#define EPB 3125          // edges per histogram block (256*3125 = 800000)
#define HALF 25000        // node-range half for LDS histogram
#define SLOTS 12500       // packed u16 pairs per half (50 KB LDS)

// ---------------------------------------------------------------------------
// ws layout (bytes):
//   [0, 25_600_000)           meta: int2[N_NODES*CAP] (src, bits(edge_w))
//                             (transiently reused as hist partials: 2*256*12500*4
//                              = 25,600,000 B exactly)
//   [25_600_000, 25_800_000)  cnt:    int[N_NODES]   in-degree (pos atomic)
//   [25_800_000, 26_000_000)  inv_od: float[N_NODES] rsqrt(max(out_deg,1))
// total 26,000,000 B. agg lives in d_out; gemm rewrites it in place.
// ---------------------------------------------------------------------------

// LDS-privatized out-degree histogram: packed u16 counters (block chunk is
// 3125 edges, so max per-block count < 65536). Two node-range halves.
__global__ __launch_bounds__(256) void hist_kernel(
    const int* __restrict__ src, unsigned* __restrict__ partial) {
    __shared__ unsigned h[SLOTS];   // 50 KB
    int b = blockIdx.x, tid = threadIdx.x;
    int e0 = b * EPB;
    int e1 = e0 + EPB;
    if (e1 > N_EDGES) e1 = N_EDGES;
    for (int h2 = 0; h2 < 2; ++h2) {
        for (int j = tid; j < SLOTS; j += 256) h[j] = 0;
        __syncthreads();
        int base = h2 * HALF;
        for (int e = e0 + tid; e < e1; e += 256) {
            int s = src[e];
            unsigned us = (unsigned)(s - base);
            if (us < HALF)
                atomicAdd(&h[us >> 1], 1u << ((s & 1) * 16));
        }
        __syncthreads();
        unsigned* po = partial + ((size_t)h2 * NB + b) * SLOTS;
        for (int j = tid; j < SLOTS; j += 256) po[j] = h[j];
        __syncthreads();   // partial flushed before re-zero for next half
    }
}

// Fold NB partials -> inv_od[] float table; also zero cnt (replaces memset).
__global__ __launch_bounds__(256) void reduce_kernel(
    const unsigned* __restrict__ partial, float* __restrict__ inv_od,
    int* __restrict__ cnt) {
    int t = blockIdx.x * blockDim.x + threadIdx.x;
    if (t >= 2 * SLOTS) return;
    int h2 = t / SLOTS, j = t - h2 * SLOTS;
    const unsigned* p = partial + (size_t)h2 * NB * SLOTS + j;
    unsigned lo = 0, hi = 0;
    for (int b = 0; b < NB; ++b) {
        unsigned v = p[(size_t)b * SLOTS];
        lo += v & 0xFFFFu;
        hi += v >> 16;
    }
    int n0 = h2 * HALF + 2 * j;
    inv_od[n0] = rsqrtf(fmaxf((float)lo, 1.0f));
    inv_od[n0 + 1] = rsqrtf(fmaxf((float)hi, 1.0f));
    cnt[n0] = 0;
    cnt[n0 + 1] = 0;
}

// Bucket placement: one pos atomic per edge (the only unavoidable atomic).
__global__ __launch_bounds__(256) void place_kernel(
    const int* __restrict__ src, const int* __restrict__ dst,
    const float* __restrict__ edge_w,
    int* __restrict__ cnt, int2* __restrict__ meta) {
    int e = blockIdx.x * blockDim.x + threadIdx.x;
    if (e >= N_EDGES) return;
    int s = src[e];
    int d = dst[e];
    int pos = atomicAdd(&cnt[d], 1);
    if (pos < CAP)
        meta[(size_t)d * CAP + pos] = make_int2(s, __float_as_int(edge_w[e]));
}

// One 64-lane wave per dst node; halves process alternate edges, 4 in flight
// per half. Each 32-lane half loads a full 512B feat row as float4.
__global__ __launch_bounds__(256) void gather_kernel(
    const float* __restrict__ feat, const int* __restrict__ cnt,
    const float* __restrict__ inv_od, const int2* __restrict__ meta,
    float* __restrict__ agg) {
    int wid = (blockIdx.x * blockDim.x + threadIdx.x) >> 6;
    if (wid >= N_NODES) return;
    int lane = threadIdx.x & 63;
    int half = lane >> 5, l = lane & 31;
    int c = cnt[wid];
    if (c > CAP) c = CAP;
    const int2* m = meta + (size_t)wid * CAP;
    float4 acc = make_float4(0.f, 0.f, 0.f, 0.f);
    int j = half;
    for (; j + 6 < c; j += 8) {          // edges j, j+2, j+4, j+6 in flight
        int2 m0 = m[j];
        int2 m1 = m[j + 2];
        int2 m2 = m[j + 4];
        int2 m3 = m[j + 6];
        float w0 = __int_as_float(m0.y) * inv_od[m0.x];
        float w1 = __int_as_float(m1.y) * inv_od[m1.x];
        float w2 = __int_as_float(m2.y) * inv_od[m2.x];
        float w3 = __int_as_float(m3.y) * inv_od[m3.x];
        float4 v0 = ((const float4*)(feat + (size_t)m0.x * F))[l];
        float4 v1 = ((const float4*)(feat + (size_t)m1.x * F))[l];
        float4 v2 = ((const float4*)(feat + (size_t)m2.x * F))[l];
        float4 v3 = ((const float4*)(feat + (size_t)m3.x * F))[l];
        acc.x += w0 * v0.x; acc.y += w0 * v0.y;
        acc.z += w0 * v0.z; acc.w += w0 * v0.w;
        acc.x += w1 * v1.x; acc.y += w1 * v1.y;
        acc.z += w1 * v1.z; acc.w += w1 * v1.w;
        acc.x += w2 * v2.x; acc.y += w2 * v2.y;
        acc.z += w2 * v2.z; acc.w += w2 * v2.w;
        acc.x += w3 * v3.x; acc.y += w3 * v3.y;
        acc.z += w3 * v3.z; acc.w += w3 * v3.w;
    }
    for (; j < c; j += 2) {
        int2 m0 = m[j];
        float w0 = __int_as_float(m0.y) * inv_od[m0.x];
        float4 v0 = ((const float4*)(feat + (size_t)m0.x * F))[l];
        acc.x += w0 * v0.x; acc.y += w0 * v0.y;
        acc.z += w0 * v0.z; acc.w += w0 * v0.w;
    }
    acc.x += __shfl_xor(acc.x, 32, 64);
    acc.y += __shfl_xor(acc.y, 32, 64);
    acc.z += __shfl_xor(acc.z, 32, 64);
    acc.w += __shfl_xor(acc.w, 32, 64);
    if (half == 0)
        ((float4*)(agg + (size_t)wid * F))[l] = acc;
}

// In-place GEMM: BM=32 rows/block, K-chunked LDS (21 KB), register prefetch
// pipeline (chunk kt+1 loads overlap chunk kt compute). Block reads only its
// own 32 rows, writes them at the end -> no inter-block hazard.
__global__ __launch_bounds__(256) void gemm_inplace(
    const float* __restrict__ W, const float* __restrict__ bias,
    const int* __restrict__ cnt, float* __restrict__ io) {
    __shared__ float As[32][36];    // K-chunk of A, +4 pad
    __shared__ float Ws[32][128];   // K-chunk of W

    int tid = threadIdx.x;
    int row0 = blockIdx.x * 32;
    int tx = tid & 15, ty = tid >> 4;

    // staging coords
    int ar = tid >> 3, ac4 = tid & 7;        // A: 1 float4 per thread
    int wr = tid >> 5, wc4 = tid & 31;       // W: 4 float4 per thread (row step 8)
    int garow = row0 + ar;

    float4 pa;
    float4 pw[4];
    // prefetch chunk 0
    pa = make_float4(0.f, 0.f, 0.f, 0.f);
    if (garow < N_NODES)
        pa = ((const float4*)(io + (size_t)garow * F))[ac4];
#pragma unroll
    for (int p = 0; p < 4; ++p)
        pw[p] = ((const float4*)(W + (size_t)(wr + p * 8) * F))[wc4];

    float acc[2][8] = {{0.f}};
    for (int kt = 0; kt < 4; ++kt) {
        *(float4*)&As[ar][ac4 * 4] = pa;
#pragma unroll
        for (int p = 0; p < 4; ++p)
            *(float4*)&Ws[wr + p * 8][wc4 * 4] = pw[p];
        __syncthreads();
        if (kt < 3) {   // issue next chunk loads; latency hidden under compute
            pa = make_float4(0.f, 0.f, 0.f, 0.f);
            if (garow < N_NODES)
                pa = ((const float4*)(io + (size_t)garow * F + (kt + 1) * 32))[ac4];
#pragma unroll
            for (int p = 0; p < 4; ++p)
                pw[p] = ((const float4*)(W + (size_t)((kt + 1) * 32 + wr + p * 8) * F))[wc4];
        }
#pragma unroll
        for (int k = 0; k < 32; ++k) {
            float a0 = As[ty * 2 + 0][k];
            float a1 = As[ty * 2 + 1][k];
            float4 b0 = *(float4*)&Ws[k][tx * 4];
            float4 b1 = *(float4*)&Ws[k][64 + tx * 4];
            acc[0][0] += a0 * b0.x; acc[0][1] += a0 * b0.y;
            acc[0][2] += a0 * b0.z; acc[0][3] += a0 * b0.w;
            acc[0][4] += a0 * b1.x; acc[0][5] += a0 * b1.y;
            acc[0][6] += a0 * b1.z; acc[0][7] += a0 * b1.w;
            acc[1][0] += a1 * b0.x; acc[1][1] += a1 * b0.y;
            acc[1][2] += a1 * b0.z; acc[1][3] += a1 * b0.w;
            acc[1][4] += a1 * b1.x; acc[1][5] += a1 * b1.y;
            acc[1][6] += a1 * b1.z; acc[1][7] += a1 * b1.w;
        }
        __syncthreads();   // chunk consumed before LDS overwrite
    }

#pragma unroll
    for (int i = 0; i < 2; ++i) {
        int gr = row0 + ty * 2 + i;
        if (gr >= N_NODES) continue;
        float sc = rsqrtf(fmaxf((float)cnt[gr], 1.0f));
        float4 o0, o1;
        o0.x = acc[i][0] * sc + bias[tx * 4 + 0];
        o0.y = acc[i][1] * sc + bias[tx * 4 + 1];
        o0.z = acc[i][2] * sc + bias[tx * 4 + 2];
        o0.w = acc[i][3] * sc + bias[tx * 4 + 3];
        o1.x = acc[i][4] * sc + bias[64 + tx * 4 + 0];
        o1.y = acc[i][5] * sc + bias[64 + tx * 4 + 1];
        o1.z = acc[i][6] * sc + bias[64 + tx * 4 + 2];
        o1.w = acc[i][7] * sc + bias[64 + tx * 4 + 3];
        ((float4*)(io + (size_t)gr * F))[tx] = o0;
        ((float4*)(io + (size_t)gr * F))[16 + tx] = o1;
    }
}

extern "C" void kernel_launch(void* const* d_in, const int* in_sizes, int n_in,
                              void* d_out, int out_size, void* d_ws, size_t ws_size,
                              hipStream_t stream) {
    const float* feat   = (const float*)d_in[0];
    const float* W      = (const float*)d_in[1];
    const float* bias   = (const float*)d_in[2];
    const float* edge_w = (const float*)d_in[3];
    const int* edge_src = (const int*)d_in[4];
    const int* edge_dst = (const int*)d_in[5];
    float* out = (float*)d_out;

    int2* meta     = (int2*)d_ws;
    int* cnt       = (int*)((char*)d_ws + (size_t)N_NODES * CAP * sizeof(int2));
    float* inv_od  = (float*)(cnt + N_NODES);
    unsigned* part = (unsigned*)d_ws;   // transient alias of meta (25.6 MB)

    hist_kernel<<<NB, 256, 0, stream>>>(edge_src, part);
    reduce_kernel<<<(2 * SLOTS + 255) / 256, 256, 0, stream>>>(part, inv_od, cnt);

    place_kernel<<<(N_EDGES + 255) / 256, 256, 0, stream>>>(
        edge_src, edge_dst, edge_w, cnt, meta);

    gather_kernel<<<(N_NODES * 64 + 255) / 256, 256, 0, stream>>>(
        feat, cnt, inv_od, meta, out);

    gemm_inplace<<<(N_NODES + 31) / 32, 256, 0, stream>>>(
        W, bias, cnt, out);
}

// Round 11
// 254.531 us; speedup vs baseline: 1.0006x; 1.0006x over previous
//
#include <hip/hip_runtime.h>
#include <math.h>

#define N_NODES 50000
#define N_EDGES 800000
#define F 128
#define CAP 64            // bucket capacity per dst; in-deg ~ Poisson(16), P(>=64) ~ 1e-19/node
#define NB 256            // histogram blocks
#define EPB 3125          // edges per histogram block (256*3125 = 800000)
#define HALF 25000        // node-range half for LDS histogram
#define SLOTS 12500       // packed u16 pairs per half (50 KB LDS)

// ---------------------------------------------------------------------------
// ws layout (bytes):
//   [0, 25_600_000)           meta: int2[N_NODES*CAP] (src, bits(edge_w))
//                             (transiently reused as hist partials: 2*256*12500*4
//                              = 25,600,000 B exactly)
//   [25_600_000, 25_800_000)  cnt:    int[N_NODES]   in-degree (pos atomic)
//   [25_800_000, 26_000_000)  inv_od: float[N_NODES] rsqrt(max(out_deg,1))
// total 26,000,000 B. agg lives in d_out; gemm rewrites it in place.
// ---------------------------------------------------------------------------

// LDS-privatized out-degree histogram: packed u16 counters (block chunk is
// 3125 edges, so max per-block count < 65536). Two node-range halves.
__global__ __launch_bounds__(256) void hist_kernel(
    const int* __restrict__ src, unsigned* __restrict__ partial) {
    __shared__ unsigned h[SLOTS];   // 50 KB
    int b = blockIdx.x, tid = threadIdx.x;
    int e0 = b * EPB;
    int e1 = e0 + EPB;
    if (e1 > N_EDGES) e1 = N_EDGES;
    for (int h2 = 0; h2 < 2; ++h2) {
        for (int j = tid; j < SLOTS; j += 256) h[j] = 0;
        __syncthreads();
        int base = h2 * HALF;
        for (int e = e0 + tid; e < e1; e += 256) {
            int s = src[e];
            unsigned us = (unsigned)(s - base);
            if (us < HALF)
                atomicAdd(&h[us >> 1], 1u << ((s & 1) * 16));
        }
        __syncthreads();
        unsigned* po = partial + ((size_t)h2 * NB + b) * SLOTS;
        for (int j = tid; j < SLOTS; j += 256) po[j] = h[j];
        __syncthreads();   // partial flushed before re-zero for next half
    }
}

// Fold NB partials -> inv_od[] float table; also zero cnt (replaces memset).
__global__ __launch_bounds__(256) void reduce_kernel(
    const unsigned* __restrict__ partial, float* __restrict__ inv_od,
    int* __restrict__ cnt) {
    int t = blockIdx.x * blockDim.x + threadIdx.x;
    if (t >= 2 * SLOTS) return;
    int h2 = t / SLOTS, j = t - h2 * SLOTS;
    const unsigned* p = partial + (size_t)h2 * NB * SLOTS + j;
    unsigned lo = 0, hi = 0;
    for (int b = 0; b < NB; ++b) {
        unsigned v = p[(size_t)b * SLOTS];
        lo += v & 0xFFFFu;
        hi += v >> 16;
    }
    int n0 = h2 * HALF + 2 * j;
    inv_od[n0] = rsqrtf(fmaxf((float)lo, 1.0f));
    inv_od[n0 + 1] = rsqrtf(fmaxf((float)hi, 1.0f));
    cnt[n0] = 0;
    cnt[n0 + 1] = 0;
}

// Bucket placement: one pos atomic per edge (the only unavoidable atomic).
__global__ __launch_bounds__(256) void place_kernel(
    const int* __restrict__ src, const int* __restrict__ dst,
    const float* __restrict__ edge_w,
    int* __restrict__ cnt, int2* __restrict__ meta) {
    int e = blockIdx.x * blockDim.x + threadIdx.x;
    if (e >= N_EDGES) return;
    int s = src[e];
    int d = dst[e];
    int pos = atomicAdd(&cnt[d], 1);
    if (pos < CAP)
        meta[(size_t)d * CAP + pos] = make_int2(s, __float_as_int(edge_w[e]));
}

// One 64-lane wave per dst node; halves process alternate edges, 2 in flight
// per half. Each 32-lane half loads a full 512B feat row as float4.
// node_base splits the node range across two dispatches (profil. visibility).
__global__ __launch_bounds__(256) void gather_kernel(
    const float* __restrict__ feat, const int* __restrict__ cnt,
    const float* __restrict__ inv_od, const int2* __restrict__ meta,
    float* __restrict__ agg, int node_base, int node_end) {
    int wid = node_base + ((blockIdx.x * blockDim.x + threadIdx.x) >> 6);
    if (wid >= node_end) return;
    int lane = threadIdx.x & 63;
    int half = lane >> 5, l = lane & 31;
    int c = cnt[wid];
    if (c > CAP) c = CAP;
    const int2* m = meta + (size_t)wid * CAP;
    float4 acc = make_float4(0.f, 0.f, 0.f, 0.f);
    int j = half;
    for (; j + 2 < c; j += 4) {          // edges j and j+2 in flight
        int2 m0 = m[j];
        int2 m1 = m[j + 2];
        float w0 = __int_as_float(m0.y) * inv_od[m0.x];
        float w1 = __int_as_float(m1.y) * inv_od[m1.x];
        float4 v0 = ((const float4*)(feat + (size_t)m0.x * F))[l];
        float4 v1 = ((const float4*)(feat + (size_t)m1.x * F))[l];
        acc.x += w0 * v0.x; acc.y += w0 * v0.y;
        acc.z += w0 * v0.z; acc.w += w0 * v0.w;
        acc.x += w1 * v1.x; acc.y += w1 * v1.y;
        acc.z += w1 * v1.z; acc.w += w1 * v1.w;
    }
    for (; j < c; j += 2) {
        int2 m0 = m[j];
        float w0 = __int_as_float(m0.y) * inv_od[m0.x];
        float4 v0 = ((const float4*)(feat + (size_t)m0.x * F))[l];
        acc.x += w0 * v0.x; acc.y += w0 * v0.y;
        acc.z += w0 * v0.z; acc.w += w0 * v0.w;
    }
    acc.x += __shfl_xor(acc.x, 32, 64);
    acc.y += __shfl_xor(acc.y, 32, 64);
    acc.z += __shfl_xor(acc.z, 32, 64);
    acc.w += __shfl_xor(acc.w, 32, 64);
    if (half == 0)
        ((float4*)(agg + (size_t)wid * F))[l] = acc;
}

// In-place GEMM: BM=64 rows/block, K-chunked LDS (25 KB), register prefetch
// double-buffer, acc[4][8] per thread (32 FMA per k-step -> better FMA:LDS
// ratio). Block reads only its own 64 rows, writes them at the end.
__global__ __launch_bounds__(256) void gemm_inplace(
    const float* __restrict__ W, const float* __restrict__ bias,
    const int* __restrict__ cnt, float* __restrict__ io) {
    __shared__ float As[64][36];    // K-chunk of A, +4 pad
    __shared__ float Ws[32][128];   // K-chunk of W

    int tid = threadIdx.x;
    int row0 = blockIdx.x * 64;
    int tx = tid & 15, ty = tid >> 4;

    // staging coords: A = 64 rows x 8 float4 = 512 -> 2 per thread
    int ar = tid >> 3, ac = tid & 7;
    int g0 = row0 + ar, g1 = row0 + 32 + ar;
    // W = 32 rows x 32 float4 = 1024 -> 4 per thread (row step 8)
    int wr = tid >> 5, wc = tid & 31;

    float4 pa0, pa1, pw[4];
    pa0 = make_float4(0.f, 0.f, 0.f, 0.f);
    pa1 = make_float4(0.f, 0.f, 0.f, 0.f);
    if (g0 < N_NODES) pa0 = ((const float4*)(io + (size_t)g0 * F))[ac];
    if (g1 < N_NODES) pa1 = ((const float4*)(io + (size_t)g1 * F))[ac];
#pragma unroll
    for (int p = 0; p < 4; ++p)
        pw[p] = ((const float4*)(W + (size_t)(wr + p * 8) * F))[wc];

    float acc[4][8] = {{0.f}};
    for (int kt = 0; kt < 4; ++kt) {
        *(float4*)&As[ar][ac * 4] = pa0;
        *(float4*)&As[32 + ar][ac * 4] = pa1;
#pragma unroll
        for (int p = 0; p < 4; ++p)
            *(float4*)&Ws[wr + p * 8][wc * 4] = pw[p];
        __syncthreads();
        if (kt < 3) {   // issue next chunk loads; latency hidden under compute
            int ko = (kt + 1) * 32;
            pa0 = make_float4(0.f, 0.f, 0.f, 0.f);
            pa1 = make_float4(0.f, 0.f, 0.f, 0.f);
            if (g0 < N_NODES) pa0 = ((const float4*)(io + (size_t)g0 * F + ko))[ac];
            if (g1 < N_NODES) pa1 = ((const float4*)(io + (size_t)g1 * F + ko))[ac];
#pragma unroll
            for (int p = 0; p < 4; ++p)
                pw[p] = ((const float4*)(W + (size_t)(ko + wr + p * 8) * F))[wc];
        }
#pragma unroll
        for (int k = 0; k < 32; ++k) {
            float a[4];
#pragma unroll
            for (int i = 0; i < 4; ++i) a[i] = As[ty * 4 + i][k];
            float4 b0 = *(float4*)&Ws[k][tx * 4];
            float4 b1 = *(float4*)&Ws[k][64 + tx * 4];
#pragma unroll
            for (int i = 0; i < 4; ++i) {
                acc[i][0] += a[i] * b0.x; acc[i][1] += a[i] * b0.y;
                acc[i][2] += a[i] * b0.z; acc[i][3] += a[i] * b0.w;
                acc[i][4] += a[i] * b1.x; acc[i][5] += a[i] * b1.y;
                acc[i][6] += a[i] * b1.z; acc[i][7] += a[i] * b1.w;
            }
        }
        __syncthreads();   // chunk consumed before LDS overwrite
    }

#pragma unroll
    for (int i = 0; i < 4; ++i) {
        int gr = row0 + ty * 4 + i;
        if (gr >= N_NODES) continue;
        float sc = rsqrtf(fmaxf((float)cnt[gr], 1.0f));
        float4 o0, o1;
        o0.x = acc[i][0] * sc + bias[tx * 4 + 0];
        o0.y = acc[i][1] * sc + bias[tx * 4 + 1];
        o0.z = acc[i][2] * sc + bias[tx * 4 + 2];
        o0.w = acc[i][3] * sc + bias[tx * 4 + 3];
        o1.x = acc[i][4] * sc + bias[64 + tx * 4 + 0];
        o1.y = acc[i][5] * sc + bias[64 + tx * 4 + 1];
        o1.z = acc[i][6] * sc + bias[64 + tx * 4 + 2];
        o1.w = acc[i][7] * sc + bias[64 + tx * 4 + 3];
        ((float4*)(io + (size_t)gr * F))[tx] = o0;
        ((float4*)(io + (size_t)gr * F))[16 + tx] = o1;
    }
}

extern "C" void kernel_launch(void* const* d_in, const int* in_sizes, int n_in,
                              void* d_out, int out_size, void* d_ws, size_t ws_size,
                              hipStream_t stream) {
    const float* feat   = (const float*)d_in[0];
    const float* W      = (const float*)d_in[1];
    const float* bias   = (const float*)d_in[2];
    const float* edge_w = (const float*)d_in[3];
    const int* edge_src = (const int*)d_in[4];
    const int* edge_dst = (const int*)d_in[5];
    float* out = (float*)d_out;

    int2* meta     = (int2*)d_ws;
    int* cnt       = (int*)((char*)d_ws + (size_t)N_NODES * CAP * sizeof(int2));
    float* inv_od  = (float*)(cnt + N_NODES);
    unsigned* part = (unsigned*)d_ws;   // transient alias of meta (25.6 MB)

    hist_kernel<<<NB, 256, 0, stream>>>(edge_src, part);
    reduce_kernel<<<(2 * SLOTS + 255) / 256, 256, 0, stream>>>(part, inv_od, cnt);

    place_kernel<<<(N_EDGES + 255) / 256, 256, 0, stream>>>(
        edge_src, edge_dst, edge_w, cnt, meta);

    // gather split into two half-range dispatches so the per-dispatch top-5
    // reveals the other kernels' true durations (attribution visibility).
    gather_kernel<<<(HALF * 64) / 256, 256, 0, stream>>>(
        feat, cnt, inv_od, meta, out, 0, HALF);
    gather_kernel<<<(HALF * 64) / 256, 256, 0, stream>>>(
        feat, cnt, inv_od, meta, out, HALF, N_NODES);

    gemm_inplace<<<(N_NODES + 63) / 64, 256, 0, stream>>>(
        W, bias, cnt, out);
}

// Round 13
// 244.333 us; speedup vs baseline: 1.0424x; 1.0417x over previous
//
#include <hip/hip_runtime.h>
#include <math.h>

#define N_NODES 50000
#define N_EDGES 800000
#define F 128
#define CAP 64            // bucket capacity per dst; in-deg ~ Poisson(16)
#define NB 128            // histogram blocks
#define EPB 6250          // edges per hist block (128*6250 = 800000; count < 65536)
#define QN 12500          // nodes per quarter-range
#define QS 6250           // packed u16 slots per quarter (25 KB LDS)

// ---------------------------------------------------------------------------
// ws layout (bytes):
//   [0, 12_800_000)           meta: u32[N_NODES*CAP]  (src<<15 | w_q15)
//                             (transiently aliased by hist partials:
//                              4*128*6250*4 = 12,800,000 B exactly)
//   [12_800_000, 25_600_000)  feat16: ushort[N_NODES*F]  bf16(RNE) copy of feat
//   [25_600_000, 25_800_000)  cnt:    int[N_NODES]
//   [25_800_000, 26_000_000)  inv_od: float[N_NODES]
// total 26,000,000 B (same proven footprint). agg lives in d_out; gemm
// rewrites it in place.
// ---------------------------------------------------------------------------

__device__ __forceinline__ float bf16_to_f(ushort h) {
    return __uint_as_float((unsigned)h << 16);
}
__device__ __forceinline__ ushort f_to_bf16(float x) {   // round-to-nearest-even
    unsigned b = __float_as_uint(x);
    return (ushort)((b + 0x7FFFu + ((b >> 16) & 1u)) >> 16);
}

// LDS-privatized out-degree histogram, 4 quarter-ranges, packed u16 counters.
__global__ __launch_bounds__(256) void hist_kernel(
    const int* __restrict__ src, unsigned* __restrict__ partial) {
    __shared__ unsigned h[QS];   // 25 KB
    int b = blockIdx.x, tid = threadIdx.x;
    int e0 = b * EPB, e1 = e0 + EPB;
    for (int q = 0; q < 4; ++q) {
        for (int j = tid; j < QS; j += 256) h[j] = 0;
        __syncthreads();
        int base = q * QN;
        for (int e = e0 + tid; e < e1; e += 256) {
            int s = src[e];
            unsigned us = (unsigned)(s - base);
            if (us < (unsigned)QN)
                atomicAdd(&h[us >> 1], 1u << ((s & 1) * 16));
        }
        __syncthreads();
        unsigned* po = partial + (size_t)(q * NB + b) * QS;
        for (int j = tid; j < QS; j += 256) po[j] = h[j];
        __syncthreads();   // flush before re-zero for next quarter
    }
}

// Fold partials -> inv_od, zero cnt, AND build bf16 feat copy (grid-stride).
// partials live in [0,12.8M); feat16 in [12.8M,25.6M) -> no overlap.
__global__ __launch_bounds__(256) void reduce_convert_kernel(
    const unsigned* __restrict__ partial, const float* __restrict__ feat,
    float* __restrict__ inv_od, int* __restrict__ cnt,
    ushort* __restrict__ feat16) {
    int gtid = blockIdx.x * blockDim.x + threadIdx.x;
    if (gtid < 4 * QS) {
        int q = gtid / QS, j = gtid - q * QS;
        const unsigned* p = partial + (size_t)q * NB * QS + j;
        unsigned lo = 0, hi = 0;
        for (int b = 0; b < NB; ++b) {
            unsigned v = p[(size_t)b * QS];
            lo += v & 0xFFFFu;
            hi += v >> 16;
        }
        int n0 = q * QN + 2 * j;
        inv_od[n0] = rsqrtf(fmaxf((float)lo, 1.0f));
        inv_od[n0 + 1] = rsqrtf(fmaxf((float)hi, 1.0f));
        cnt[n0] = 0;
        cnt[n0 + 1] = 0;
    }
    // bf16 conversion: 6.4M floats as 1.6M float4 groups
    int nthr = gridDim.x * blockDim.x;
    for (int i = gtid; i < N_NODES * F / 4; i += nthr) {
        float4 v = ((const float4*)feat)[i];
        ushort4 o;
        o.x = f_to_bf16(v.x);
        o.y = f_to_bf16(v.y);
        o.z = f_to_bf16(v.z);
        o.w = f_to_bf16(v.w);
        ((ushort4*)feat16)[i] = o;
    }
}

// Bucket placement: one pos atomic per edge; meta packed to u32.
__global__ __launch_bounds__(256) void place_kernel(
    const int* __restrict__ src, const int* __restrict__ dst,
    const float* __restrict__ edge_w,
    int* __restrict__ cnt, unsigned* __restrict__ meta) {
    int e = blockIdx.x * blockDim.x + threadIdx.x;
    if (e >= N_EDGES) return;
    int s = src[e];
    int d = dst[e];
    int wq = (int)(edge_w[e] * 32767.0f + 0.5f);
    if (wq > 32767) wq = 32767;
    int pos = atomicAdd(&cnt[d], 1);
    if (pos < CAP)
        meta[(size_t)d * CAP + pos] = ((unsigned)s << 15) | (unsigned)wq;
}

// One 64-lane wave per dst node; halves process alternate edges, 2 in flight.
// Each 32-lane half loads a full 256B bf16 feat row as ushort4 (8B/lane).
__global__ __launch_bounds__(256) void gather_kernel(
    const ushort* __restrict__ feat16, const int* __restrict__ cnt,
    const float* __restrict__ inv_od, const unsigned* __restrict__ meta,
    float* __restrict__ agg, int node_base, int node_end) {
    int wid = node_base + ((blockIdx.x * blockDim.x + threadIdx.x) >> 6);
    if (wid >= node_end) return;
    int lane = threadIdx.x & 63;
    int half = lane >> 5, l = lane & 31;
    int c = cnt[wid];
    if (c > CAP) c = CAP;
    const unsigned* m = meta + (size_t)wid * CAP;
    float4 acc = make_float4(0.f, 0.f, 0.f, 0.f);
    const float wsc = 1.0f / 32767.0f;
    int j = half;
    for (; j + 2 < c; j += 4) {          // edges j and j+2 in flight
        unsigned u0 = m[j];
        unsigned u1 = m[j + 2];
        int s0 = u0 >> 15, s1 = u1 >> 15;
        float w0 = (float)(u0 & 32767u) * wsc * inv_od[s0];
        float w1 = (float)(u1 & 32767u) * wsc * inv_od[s1];
        ushort4 v0 = ((const ushort4*)(feat16 + (size_t)s0 * F))[l];
        ushort4 v1 = ((const ushort4*)(feat16 + (size_t)s1 * F))[l];
        acc.x += w0 * bf16_to_f(v0.x); acc.y += w0 * bf16_to_f(v0.y);
        acc.z += w0 * bf16_to_f(v0.z); acc.w += w0 * bf16_to_f(v0.w);
        acc.x += w1 * bf16_to_f(v1.x); acc.y += w1 * bf16_to_f(v1.y);
        acc.z += w1 * bf16_to_f(v1.z); acc.w += w1 * bf16_to_f(v1.w);
    }
    for (; j < c; j += 2) {
        unsigned u0 = m[j];
        int s0 = u0 >> 15;
        float w0 = (float)(u0 & 32767u) * wsc * inv_od[s0];
        ushort4 v0 = ((const ushort4*)(feat16 + (size_t)s0 * F))[l];
        acc.x += w0 * bf16_to_f(v0.x); acc.y += w0 * bf16_to_f(v0.y);
        acc.z += w0 * bf16_to_f(v0.z); acc.w += w0 * bf16_to_f(v0.w);
    }
    acc.x += __shfl_xor(acc.x, 32, 64);
    acc.y += __shfl_xor(acc.y, 32, 64);
    acc.z += __shfl_xor(acc.z, 32, 64);
    acc.w += __shfl_xor(acc.w, 32, 64);
    if (half == 0)
        ((float4*)(agg + (size_t)wid * F))[l] = acc;
}

// In-place GEMM: BM=64 rows/block, K-chunked LDS (25 KB), register prefetch
// double-buffer, acc[4][8] per thread. Block owns its 64 rows exclusively.
__global__ __launch_bounds__(256) void gemm_inplace(
    const float* __restrict__ W, const float* __restrict__ bias,
    const int* __restrict__ cnt, float* __restrict__ io) {
    __shared__ float As[64][36];    // K-chunk of A, +4 pad
    __shared__ float Ws[32][128];   // K-chunk of W

    int tid = threadIdx.x;
    int row0 = blockIdx.x * 64;
    int tx = tid & 15, ty = tid >> 4;

    int ar = tid >> 3, ac = tid & 7;
    int g0 = row0 + ar, g1 = row0 + 32 + ar;
    int wr = tid >> 5, wc = tid & 31;

    float4 pa0, pa1, pw[4];
    pa0 = make_float4(0.f, 0.f, 0.f, 0.f);
    pa1 = make_float4(0.f, 0.f, 0.f, 0.f);
    if (g0 < N_NODES) pa0 = ((const float4*)(io + (size_t)g0 * F))[ac];
    if (g1 < N_NODES) pa1 = ((const float4*)(io + (size_t)g1 * F))[ac];
#pragma unroll
    for (int p = 0; p < 4; ++p)
        pw[p] = ((const float4*)(W + (size_t)(wr + p * 8) * F))[wc];

    float acc[4][8] = {{0.f}};
    for (int kt = 0; kt < 4; ++kt) {
        *(float4*)&As[ar][ac * 4] = pa0;
        *(float4*)&As[32 + ar][ac * 4] = pa1;
#pragma unroll
        for (int p = 0; p < 4; ++p)
            *(float4*)&Ws[wr + p * 8][wc * 4] = pw[p];
        __syncthreads();
        if (kt < 3) {
            int ko = (kt + 1) * 32;
            pa0 = make_float4(0.f, 0.f, 0.f, 0.f);
            pa1 = make_float4(0.f, 0.f, 0.f, 0.f);
            if (g0 < N_NODES) pa0 = ((const float4*)(io + (size_t)g0 * F + ko))[ac];
            if (g1 < N_NODES) pa1 = ((const float4*)(io + (size_t)g1 * F + ko))[ac];
#pragma unroll
            for (int p = 0; p < 4; ++p)
                pw[p] = ((const float4*)(W + (size_t)(ko + wr + p * 8) * F))[wc];
        }
#pragma unroll
        for (int k = 0; k < 32; ++k) {
            float a[4];
#pragma unroll
            for (int i = 0; i < 4; ++i) a[i] = As[ty * 4 + i][k];
            float4 b0 = *(float4*)&Ws[k][tx * 4];
            float4 b1 = *(float4*)&Ws[k][64 + tx * 4];
#pragma unroll
            for (int i = 0; i < 4; ++i) {
                acc[i][0] += a[i] * b0.x; acc[i][1] += a[i] * b0.y;
                acc[i][2] += a[i] * b0.z; acc[i][3] += a[i] * b0.w;
                acc[i][4] += a[i] * b1.x; acc[i][5] += a[i] * b1.y;
                acc[i][6] += a[i] * b1.z; acc[i][7] += a[i] * b1.w;
            }
        }
        __syncthreads();
    }

#pragma unroll
    for (int i = 0; i < 4; ++i) {
        int gr = row0 + ty * 4 + i;
        if (gr >= N_NODES) continue;
        float sc = rsqrtf(fmaxf((float)cnt[gr], 1.0f));
        float4 o0, o1;
        o0.x = acc[i][0] * sc + bias[tx * 4 + 0];
        o0.y = acc[i][1] * sc + bias[tx * 4 + 1];
        o0.z = acc[i][2] * sc + bias[tx * 4 + 2];
        o0.w = acc[i][3] * sc + bias[tx * 4 + 3];
        o1.x = acc[i][4] * sc + bias[64 + tx * 4 + 0];
        o1.y = acc[i][5] * sc + bias[64 + tx * 4 + 1];
        o1.z = acc[i][6] * sc + bias[64 + tx * 4 + 2];
        o1.w = acc[i][7] * sc + bias[64 + tx * 4 + 3];
        ((float4*)(io + (size_t)gr * F))[tx] = o0;
        ((float4*)(io + (size_t)gr * F))[16 + tx] = o1;
    }
}

extern "C" void kernel_launch(void* const* d_in, const int* in_sizes, int n_in,
                              void* d_out, int out_size, void* d_ws, size_t ws_size,
                              hipStream_t stream) {
    const float* feat   = (const float*)d_in[0];
    const float* W      = (const float*)d_in[1];
    const float* bias   = (const float*)d_in[2];
    const float* edge_w = (const float*)d_in[3];
    const int* edge_src = (const int*)d_in[4];
    const int* edge_dst = (const int*)d_in[5];
    float* out = (float*)d_out;

    unsigned* meta  = (unsigned*)d_ws;
    ushort* feat16  = (ushort*)((char*)d_ws + (size_t)N_NODES * CAP * 4);
    int* cnt        = (int*)((char*)d_ws + 25600000);
    float* inv_od   = (float*)(cnt + N_NODES);
    unsigned* part  = (unsigned*)d_ws;   // transient alias of meta (12.8 MB)

    hist_kernel<<<NB, 256, 0, stream>>>(edge_src, part);

    reduce_convert_kernel<<<512, 256, 0, stream>>>(
        part, feat, inv_od, cnt, feat16);

    place_kernel<<<(N_EDGES + 255) / 256, 256, 0, stream>>>(
        edge_src, edge_dst, edge_w, cnt, meta);

    gather_kernel<<<(25000 * 64) / 256, 256, 0, stream>>>(
        feat16, cnt, inv_od, meta, out, 0, 25000);
    gather_kernel<<<(25000 * 64) / 256, 256, 0, stream>>>(
        feat16, cnt, inv_od, meta, out, 25000, N_NODES);

    gemm_inplace<<<(N_NODES + 63) / 64, 256, 0, stream>>>(
        W, bias, cnt, out);
}